// Round 13
// baseline (254.015 us; speedup 1.0000x reference)
//
#include <hip/hip_runtime.h>
#include <stdint.h>
#include <stddef.h>

typedef _Float16 f16;
typedef _Float16 f16x8 __attribute__((ext_vector_type(8)));
typedef _Float16 f16x4 __attribute__((ext_vector_type(4)));
typedef float f32x4 __attribute__((ext_vector_type(4)));

__device__ __forceinline__ void gload16(const void* g, void* l) {
    auto gp = (const __attribute__((address_space(1))) uint32_t*)(uintptr_t)g;
    auto lp = (__attribute__((address_space(3))) uint32_t*)(uintptr_t)l;
    __builtin_amdgcn_global_load_lds(gp, lp, 16, 0, 0);
}

__device__ __forceinline__ f16x4 cvt4(f32x4 v) {
    return f16x4{ (f16)v[0], (f16)v[1], (f16)v[2], (f16)v[3] };
}

// ---------------- prep: f32 -> f16 conversions --------------------------------
__global__ __launch_bounds__(256) void prep_k(const float* __restrict__ x,
                                              const float* __restrict__ wqkv,
                                              const float* __restrict__ wout,
                                              f16* __restrict__ xb,
                                              f16* __restrict__ wqb,
                                              f16* __restrict__ wob) {
    int tid = blockIdx.x * blockDim.x + threadIdx.x;
    int stride = gridDim.x * blockDim.x;
    for (int i = tid; i < 4194304; i += stride) {
        float4 v = ((const float4*)x)[i];
        *(f16x4*)(xb + (size_t)i * 4) = f16x4{ (f16)v.x, (f16)v.y, (f16)v.z, (f16)v.w };
    }
    for (int i = tid; i < 196608; i += stride) {
        float4 v = ((const float4*)wqkv)[i];
        *(f16x4*)(wqb + (size_t)i * 4) = f16x4{ (f16)v.x, (f16)v.y, (f16)v.z, (f16)v.w };
    }
    for (int i = tid; i < 65536; i += stride) {
        float4 v = ((const float4*)wout)[i];
        *(f16x4*)(wob + (size_t)i * 4) = f16x4{ (f16)v.x, (f16)v.y, (f16)v.z, (f16)v.w };
    }
}

#define W0  asm volatile("s_waitcnt vmcnt(0)" ::: "memory")
#define BAR __builtin_amdgcn_s_barrier()

// ================= ENGINE D: g14 = g10 + B-direct-from-global =================
// 128x128 tile, BK=64, 4 waves, A staged in dbuf LDS (2x16KB), B fragments
// loaded straight from global (L2-resident weights) into registers — halves
// LDS reads and staging vs g10.  Per tile: stage A(t+1) + load bG(t+1) ->
// MM3(cur) -> vmcnt(0) -> BAR -> RD_A(t+1) -> MMLAST(cur).
// Used for: QKV Q/K (normal, permuted rows), QKV V (swapped), OUT (swapped).

#define D_STAGE(NB) do {                                                        \
    gload16(Ab + kb + sE,          &ldsA[NB][( 0 + wid*8)*64]);                 \
    gload16(Ab + kb + sO + 32768,  &ldsA[NB][(32 + wid*8)*64]);                 \
    gload16(Ab + kb + sE + 65536,  &ldsA[NB][(64 + wid*8)*64]);                 \
    gload16(Ab + kb + sO + 98304,  &ldsA[NB][(96 + wid*8)*64]);                 \
    kb += 128;                                                                  \
} while (0)

#define D_LOADB(SET) do {                                                       \
    _Pragma("unroll") for (int ni = 0; ni < 4; ++ni)                            \
    _Pragma("unroll") for (int kk = 0; kk < 2; ++kk)                            \
        bG##SET[ni][kk] = *(const f16x8*)(Bg + vb[ni] + kk * 64);               \
    Bg += 128;                                                                  \
} while (0)

#define D_RDA(SET, BUF) do {                                                    \
    _Pragma("unroll") for (int mi = 0; mi < 4; ++mi)                            \
    _Pragma("unroll") for (int kk = 0; kk < 2; ++kk)                            \
        aF##SET[mi][kk] = *(const f16x8*)(&ldsA[BUF][0] + aoff[mi][kk]);        \
} while (0)

#define D_MM(SET, KK, ML, MH_) do {                                             \
    __builtin_amdgcn_s_setprio(1);                                              \
    _Pragma("unroll") for (int mi = ML; mi < MH_; ++mi)                         \
    _Pragma("unroll") for (int ni = 0; ni < 4; ++ni) {                          \
        if constexpr (SWP)                                                      \
            acc[mi][ni] = __builtin_amdgcn_mfma_f32_16x16x32_f16(               \
                bG##SET[ni][KK], aF##SET[mi][KK], acc[mi][ni], 0, 0, 0);        \
        else                                                                    \
            acc[mi][ni] = __builtin_amdgcn_mfma_f32_16x16x32_f16(               \
                aF##SET[mi][KK], bG##SET[ni][KK], acc[mi][ni], 0, 0, 0);        \
    }                                                                           \
    __builtin_amdgcn_s_setprio(0);                                              \
} while (0)

#define D_MM3(SET)   do { D_MM(SET, 0, 0, 2); D_MM(SET, 0, 2, 4); D_MM(SET, 1, 0, 2); } while (0)
#define D_MMLAST(SET) D_MM(SET, 1, 2, 4)

#define D_TILE(CUR, NXT, NB, STG, FINAL) do {                                   \
    if (STG) { D_STAGE(NB); D_LOADB(NXT); }                                     \
    D_MM3(CUR);                                                                 \
    if (!FINAL) { W0; BAR; D_RDA(NXT, NB); }                                    \
    D_MMLAST(CUR);                                                              \
} while (0)

// MODE 0 + QK:  Q/K part (normal mfma, permuted A rows) -> Q/K [bh][c][lh]
// MODE 0 + SWP: V part (swapped) -> V [bh][lh][d]
// MODE 3 + SWP: out = y w_out^T + b_out (f32 out + bias)
template <int MODE, bool SWP, bool QK>
__global__ __launch_bounds__(256, 2) void g14_k(const f16* __restrict__ A0,
                                                const f16* __restrict__ B0,
                                                void* __restrict__ C0,
                                                void* __restrict__ C1,
                                                const float* __restrict__ bias) {
    __shared__ f16 ldsA[2][8192];   // 2 x 128x64, 32 KiB

    const int tid = threadIdx.x;
    const int lane = tid & 63;
    const int wid = tid >> 6;
    const int wr = wid >> 1;
    const int wc = wid & 1;
    const int g = lane >> 4;
    const int li = lane & 15;

    const int bid = blockIdx.x;
    int tm, tn;
    if constexpr (MODE == 0 && QK) {
        int swz = (bid & 7) * 256 + (bid >> 3);       // 2048 blocks
        tm = (swz >> 3) * 128; tn = (swz & 7) * 128;
    } else {
        int swz = (bid & 7) * 128 + (bid >> 3);       // 1024 blocks
        tm = (swz >> 2) * 128; tn = (swz & 3) * 128;
    }

    const char* Ab = (const char*)(A0 + (size_t)tm * 512);
    const char* Bg = (const char*)(B0 + (size_t)tn * 512);

    const int u = tid >> 3;
    const int colE = ((tid & 7) ^ ((u & 7) ^ (u >> 3))) * 16;
    const int sE = u * 1024 + colE;
    const int sO = sE ^ 64;
    int kb = 0;

    // B fragment per-lane byte offsets (no swizzle; direct global)
    int vb[4];
#pragma unroll
    for (int ni = 0; ni < 4; ++ni)
        vb[ni] = (wc * 64 + ni * 16 + li) * 1024 + g * 16;

    // A fragment LDS offsets (swizzled)
    int aoff[4][2];
#pragma unroll
    for (int mi = 0; mi < 4; ++mi) {
        int r;
        if constexpr (QK) {
            r = li * 8 + wr * 4 + mi;
        } else {
            r = wr * 64 + mi * 16 + li;
        }
#pragma unroll
        for (int kk = 0; kk < 2; ++kk) {
            int c8 = g + kk * 4;
            aoff[mi][kk] = r * 64 + (c8 ^ ((r & 7) ^ ((r >> 3) & 7))) * 8;
        }
    }

    f32x4 acc[4][4] = {};
    f16x8 aF0[4][2], aF1[4][2], bG0[4][2], bG1[4][2];

    D_STAGE(0);
    D_LOADB(0);
    W0; BAR;
    D_RDA(0, 0);

#pragma unroll 1
    for (int i = 0; i < 3; ++i) {
        D_TILE(0, 1, 1, true, false);
        D_TILE(1, 0, 0, true, false);
    }
    D_TILE(0, 1, 1, true, false);   // t6
    D_TILE(1, 1, 1, false, true);   // t7

    if constexpr (MODE == 0 && QK) {
        const int b = tm >> 12;
        const int lt = (tm & 4095) >> 3;
        f16* dst = (f16*)(tn < 512 ? C0 : C1);
        const int cb = (tn & 511) + wc * 64;
        const int lh0 = lt + g * 4;
#pragma unroll
        for (int mi = 0; mi < 4; ++mi) {
            int h = wr * 4 + mi;
#pragma unroll
            for (int ni = 0; ni < 4; ++ni) {
                int c = cb + ni * 16 + li;
                *(f16x4*)(dst + ((size_t)((b * 8 + h) * 512 + c)) * 512 + lh0) =
                    cvt4(acc[mi][ni]);
            }
        }
    } else if constexpr (MODE == 0) {      // V, swapped
        f16* dst = (f16*)C0;
#pragma unroll
        for (int mi = 0; mi < 4; ++mi) {
            int t = tm + wr * 64 + mi * 16 + li;
            int b = t >> 12, l = t & 4095;
            int h = l & 7, lh = l >> 3;
#pragma unroll
            for (int ni = 0; ni < 4; ++ni) {
                int d0 = tn + wc * 64 + ni * 16 + g * 4;
                *(f16x4*)(dst + ((size_t)((b * 8 + h) * 512 + lh)) * 512 + d0) =
                    cvt4(acc[mi][ni]);
            }
        }
    } else {                               // OUT, swapped, f32 + bias
        float* O = (float*)C0;
#pragma unroll
        for (int mi = 0; mi < 4; ++mi) {
            int m = tm + wr * 64 + mi * 16 + li;
#pragma unroll
            for (int ni = 0; ni < 4; ++ni) {
                int n0 = tn + wc * 64 + ni * 16 + g * 4;
                float4 bv = *(const float4*)(bias + n0);
                f32x4 v = acc[mi][ni];
                v[0] += bv.x; v[1] += bv.y; v[2] += bv.z; v[3] += bv.w;
                *(f32x4*)(O + (size_t)m * 512 + n0) = v;
            }
        }
    }
}

// ================== ENGINE S: fused S-GEMM + softmax (r12 verbatim) ===========
#define S_STAGE(B) do {                                                         \
    gload16(Qt + kb + soff,           &ldsQ[B][(  0 + wid*8)*64]);              \
    gload16(Qt + kb + soff + 65536,   &ldsQ[B][( 64 + wid*8)*64]);              \
    gload16(Kt + kb + soff,           &ldsK[B][(  0 + wid*8)*64]);              \
    gload16(Kt + kb + soff + 65536,   &ldsK[B][( 64 + wid*8)*64]);              \
    gload16(Kt + kb + soff + 131072,  &ldsK[B][(128 + wid*8)*64]);              \
    gload16(Kt + kb + soff + 196608,  &ldsK[B][(192 + wid*8)*64]);              \
    gload16(Kt + kb + soff + 262144,  &ldsK[B][(256 + wid*8)*64]);              \
    gload16(Kt + kb + soff + 327680,  &ldsK[B][(320 + wid*8)*64]);              \
    gload16(Kt + kb + soff + 393216,  &ldsK[B][(384 + wid*8)*64]);              \
    gload16(Kt + kb + soff + 458752,  &ldsK[B][(448 + wid*8)*64]);              \
    kb += 128;                                                                  \
} while (0)

#define S_RD(KK, B) do {                                                        \
    _Pragma("unroll") for (int ni = 0; ni < 4; ++ni)                            \
        bF[ni] = *(const f16x8*)(&ldsK[B][0] + boff[ni][KK]);                   \
    _Pragma("unroll") for (int mi = 0; mi < 8; ++mi)                            \
        aF[mi] = *(const f16x8*)(&ldsQ[B][0] + aoff[mi][KK]);                   \
} while (0)

#define S_MM do {                                                               \
    __builtin_amdgcn_s_setprio(1);                                              \
    _Pragma("unroll") for (int mi = 0; mi < 8; ++mi)                            \
    _Pragma("unroll") for (int ni = 0; ni < 4; ++ni)                            \
        acc[mi][ni] = __builtin_amdgcn_mfma_f32_16x16x32_f16(                   \
            aF[mi], bF[ni], acc[mi][ni], 0, 0, 0);                              \
    __builtin_amdgcn_s_setprio(0);                                              \
} while (0)

__global__ __launch_bounds__(512) void sfm_k(const f16* __restrict__ Qb,
                                             const f16* __restrict__ Kb,
                                             f16* __restrict__ Pb) {
    __shared__ f16 ldsQ[2][8192];     // 32 KB
    __shared__ f16 ldsK[2][32768];    // 128 KB

    const int tid = threadIdx.x;
    const int lane = tid & 63;
    const int wid = tid >> 6;
    const int g = lane >> 4;
    const int li = lane & 15;

    const int bid = blockIdx.x;
    const int swz = (bid & 7) * 32 + (bid >> 3);
    const int bh = swz >> 2, ct = swz & 3;

    const char* Qt = (const char*)(Qb + (size_t)bh * 262144 + (size_t)ct * 128 * 512);
    const char* Kt = (const char*)(Kb + (size_t)bh * 262144);

    const int soff = (tid >> 3) * 1024 +
                     ((((lane & 7) ^ (lane >> 3) ^ wid) & 7) * 16);
    int kb = 0;

    int aoff[8][2], boff[4][2];
#pragma unroll
    for (int mi = 0; mi < 8; ++mi) {
        int r = mi * 16 + li;
        int s3 = (r & 7) ^ ((r >> 3) & 7);
#pragma unroll
        for (int kk = 0; kk < 2; ++kk)
            aoff[mi][kk] = r * 64 + (((g + kk * 4) ^ s3)) * 8;
    }
#pragma unroll
    for (int ni = 0; ni < 4; ++ni) {
        int r = wid * 64 + ni * 16 + li;
        int s3 = (r & 7) ^ ((r >> 3) & 7);
#pragma unroll
        for (int kk = 0; kk < 2; ++kk)
            boff[ni][kk] = r * 64 + (((g + kk * 4) ^ s3)) * 8;
    }

    f32x4 acc[8][4] = {};
    f16x8 aF[8], bF[4];

    S_STAGE(0);
#pragma unroll 1
    for (int t = 0; t < 8; ++t) {
        const int cb = t & 1;
        if (t < 7) {
            S_STAGE(cb ^ 1);
            asm volatile("s_waitcnt vmcnt(10)" ::: "memory");
        } else {
            W0;
        }
        BAR;
        S_RD(0, cb);
        S_MM;
        S_RD(1, cb);
        S_MM;
        BAR;
    }

    float* red  = (float*)&ldsQ[0][0];
    float* redg = (float*)&ldsK[0][0];

#pragma unroll
    for (int mi = 0; mi < 8; ++mi)
#pragma unroll
        for (int ni = 0; ni < 4; ++ni) acc[mi][ni] *= 0.125f;

#pragma unroll
    for (int mi = 0; mi < 8; ++mi)
#pragma unroll
        for (int j = 0; j < 4; ++j) {
            float v = fmaxf(fmaxf(acc[mi][0][j], acc[mi][1][j]),
                            fmaxf(acc[mi][2][j], acc[mi][3][j]));
#pragma unroll
            for (int off = 1; off < 16; off <<= 1) v = fmaxf(v, __shfl_xor(v, off, 64));
            if (li == 0) red[wid * 128 + mi * 16 + g * 4 + j] = v;
        }
    BAR;
    if (tid < 128) {
        float m = red[tid];
#pragma unroll
        for (int w = 1; w < 8; ++w) m = fmaxf(m, red[w * 128 + tid]);
        redg[tid] = m;
    }
    BAR;

#pragma unroll
    for (int mi = 0; mi < 8; ++mi)
#pragma unroll
        for (int j = 0; j < 4; ++j) {
            float mg = redg[mi * 16 + g * 4 + j];
            float s = 0.f;
#pragma unroll
            for (int ni = 0; ni < 4; ++ni) {
                float e = __expf(acc[mi][ni][j] - mg);
                acc[mi][ni][j] = e;
                s += e;
            }
#pragma unroll
            for (int off = 1; off < 16; off <<= 1) s += __shfl_xor(s, off, 64);
            if (li == 0) red[wid * 128 + mi * 16 + g * 4 + j] = s;
        }
    BAR;
    if (tid < 128) {
        float s = red[tid];
#pragma unroll
        for (int w = 1; w < 8; ++w) s += red[w * 128 + tid];
        redg[tid] = 1.0f / s;
    }
    BAR;

    f16* Pt = Pb + (size_t)bh * 262144;
#pragma unroll
    for (int mi = 0; mi < 8; ++mi)
#pragma unroll
        for (int j = 0; j < 4; ++j) {
            int row = mi * 16 + g * 4 + j;
            float is = redg[row];
            size_t base = (size_t)(ct * 128 + row) * 512 + wid * 64 + li;
#pragma unroll
            for (int ni = 0; ni < 4; ++ni)
                Pt[base + ni * 16] = (f16)(acc[mi][ni][j] * is);
        }
}

// ======================= ENGINE B: g12 MODE2 (PV, r9 verbatim) ================
#define B_STAGE(NB) do {                                                        \
    gload16(At + soff,          &ldsA2[NB][(  0 + wid*8)*64]);                  \
    gload16(At + soff + 65536,  &ldsA2[NB][( 64 + wid*8)*64]);                  \
    gload16(At + soff + 131072, &ldsA2[NB][(128 + wid*8)*64]);                  \
    gload16(At + soff + 196608, &ldsA2[NB][(192 + wid*8)*64]);                  \
    gload16(Bt + soff,          &ldsB2[NB][(  0 + wid*8)*64]);                  \
    gload16(Bt + soff + 65536,  &ldsB2[NB][( 64 + wid*8)*64]);                  \
    gload16(Bt + soff + 131072, &ldsB2[NB][(128 + wid*8)*64]);                  \
    gload16(Bt + soff + 196608, &ldsB2[NB][(192 + wid*8)*64]);                  \
    At += 128; Bt += 128;                                                       \
} while (0)

#define B_RD12(KK, BUF) do {                                                    \
    _Pragma("unroll") for (int ni = 0; ni < 4; ++ni)                            \
        bF[ni] = *(const f16x8*)(&ldsB2[BUF][0] + boff[ni][KK]);                \
    _Pragma("unroll") for (int mi = 0; mi < 8; ++mi)                            \
        aF[mi] = *(const f16x8*)(&ldsA2[BUF][0] + aoff[mi][KK]);                \
} while (0)

#define B_MM32 do {                                                             \
    __builtin_amdgcn_s_setprio(1);                                              \
    _Pragma("unroll") for (int mi = 0; mi < 8; ++mi)                            \
    _Pragma("unroll") for (int ni = 0; ni < 4; ++ni)                            \
        acc[mi][ni] = __builtin_amdgcn_mfma_f32_16x16x32_f16(                   \
            aF[mi], bF[ni], acc[mi][ni], 0, 0, 0);                              \
    __builtin_amdgcn_s_setprio(0);                                              \
} while (0)

#define B_TILE(CB, NB, STG, FINAL) do {                                         \
    B_RD12(0, CB);                                                              \
    if (STG) B_STAGE(NB);                                                       \
    B_MM32;                                                                     \
    B_RD12(1, CB);                                                              \
    B_MM32;                                                                     \
    if (!FINAL) { W0; BAR; }                                                    \
} while (0)

__global__ __launch_bounds__(512) void pv_k(const f16* __restrict__ A0,
                                            const f16* __restrict__ B0,
                                            f16* __restrict__ C0) {
    __shared__ f16 ldsA2[2][16384];
    __shared__ f16 ldsB2[2][16384];

    const int tid = threadIdx.x;
    const int lane = tid & 63;
    const int wid = tid >> 6;
    const int wr = wid >> 2;
    const int wc = wid & 3;

    const int bid = blockIdx.x;
    int swz = (bid & 7) * 32 + (bid >> 3);
    int bh = swz >> 2, tm = ((swz >> 1) & 1) * 256, tn = (swz & 1) * 256;

    const size_t bhoff = (size_t)bh * 262144;
    const char* At = (const char*)(A0 + bhoff + (size_t)tm * 512);
    const char* Bt = (const char*)(B0 + bhoff + (size_t)tn * 512);

    const int soff = wid * 8192 + (lane >> 3) * 1024 +
                     ((((lane & 7) ^ (lane >> 3) ^ wid) & 7) * 16);

    int aoff[8][2], boff[4][2];
#pragma unroll
    for (int mi = 0; mi < 8; ++mi) {
        int r = wr * 128 + mi * 16 + (lane & 15);
        int s3 = (r & 7) ^ ((r >> 3) & 7);
#pragma unroll
        for (int kk = 0; kk < 2; ++kk)
            aoff[mi][kk] = r * 64 + ((((lane >> 4) + kk * 4) ^ s3)) * 8;
    }
#pragma unroll
    for (int ni = 0; ni < 4; ++ni) {
        int r = wc * 64 + ni * 16 + (lane & 15);
        int s3 = (r & 7) ^ ((r >> 3) & 7);
#pragma unroll
        for (int kk = 0; kk < 2; ++kk)
            boff[ni][kk] = r * 64 + ((((lane >> 4) + kk * 4) ^ s3)) * 8;
    }

    f32x4 acc[8][4] = {};
    f16x8 aF[8], bF[4];

    B_STAGE(0);
    W0; BAR;

#pragma unroll 1
    for (int i = 0; i < 3; ++i) {
        B_TILE(0, 1, true, false);
        B_TILE(1, 0, true, false);
    }
    B_TILE(0, 1, true, false);
    B_TILE(1, 1, false, true);

    f16* yb = C0;
    const int b = bh >> 3, h = bh & 7;
#pragma unroll
    for (int mi = 0; mi < 8; ++mi) {
        int c0 = tm + wr * 128 + mi * 16 + (lane >> 4) * 4;
#pragma unroll
        for (int ni = 0; ni < 4; ++ni) {
            int l = tn + wc * 64 + ni * 16 + (lane & 15);
            size_t tok = (size_t)b * 4096 + (size_t)l * 8 + h;
            *(f16x4*)(yb + tok * 512 + c0) = cvt4(acc[mi][ni]);
        }
    }
}

// ---------------- launch ------------------------------------------------------
extern "C" void kernel_launch(void* const* d_in, const int* in_sizes, int n_in,
                              void* d_out, int out_size, void* d_ws, size_t ws_size,
                              hipStream_t stream) {
    const float* x = (const float*)d_in[0];
    const float* wqkv = (const float*)d_in[1];
    const float* wout = (const float*)d_in[2];
    const float* bout = (const float*)d_in[3];
    float* out = (float*)d_out;
    char* ws = (char*)d_ws;
    const size_t MBs = 1u << 20;

    f16* xb  = (f16*)(ws + 0);            // 32MB
    f16* wqb = (f16*)(ws + 32 * MBs);     // 1.5MB
    f16* wob = (f16*)(ws + 34 * MBs);     // 0.5MB
    f16* Qb  = (f16*)(ws + 35 * MBs);     // 32MB
    f16* Kb  = (f16*)(ws + 67 * MBs);     // 32MB
    f16* Vb  = (f16*)(ws + 99 * MBs);     // 32MB
    f16* Pb  = xb;                        // alias: xb dead after V GEMM
    f16* yb  = Qb;                        // alias: Q dead after sfm

    prep_k<<<1024, 256, 0, stream>>>(x, wqkv, wout, xb, wqb, wob);
    g14_k<0, false, true><<<2048, 256, 0, stream>>>(xb, wqb, Qb, Kb, nullptr);
    g14_k<0, true, false><<<1024, 256, 0, stream>>>(xb, wqb + (size_t)1024 * 512, Vb, nullptr, nullptr);
    sfm_k<<<256, 512, 0, stream>>>(Qb, Kb, Pb);
    pv_k<<<256, 512, 0, stream>>>(Pb, Vb, yb);
    g14_k<3, true, false><<<1024, 256, 0, stream>>>(yb, wob, out, nullptr, bout);
}

// Round 14
// 188.224 us; speedup vs baseline: 1.3495x; 1.3495x over previous
//
#include <hip/hip_runtime.h>
#include <stdint.h>
#include <stddef.h>

typedef _Float16 f16;
typedef _Float16 f16x8 __attribute__((ext_vector_type(8)));
typedef _Float16 f16x4 __attribute__((ext_vector_type(4)));
typedef float f32x4 __attribute__((ext_vector_type(4)));

__device__ __forceinline__ void gload16(const void* g, void* l) {
    auto gp = (const __attribute__((address_space(1))) uint32_t*)(uintptr_t)g;
    auto lp = (__attribute__((address_space(3))) uint32_t*)(uintptr_t)l;
    __builtin_amdgcn_global_load_lds(gp, lp, 16, 0, 0);
}

__device__ __forceinline__ f16x4 cvt4(f32x4 v) {
    return f16x4{ (f16)v[0], (f16)v[1], (f16)v[2], (f16)v[3] };
}

// ---------------- prep: f32 -> f16 conversions --------------------------------
__global__ __launch_bounds__(256) void prep_k(const float* __restrict__ x,
                                              const float* __restrict__ wqkv,
                                              const float* __restrict__ wout,
                                              f16* __restrict__ xb,
                                              f16* __restrict__ wqb,
                                              f16* __restrict__ wob) {
    int tid = blockIdx.x * blockDim.x + threadIdx.x;
    int stride = gridDim.x * blockDim.x;
    for (int i = tid; i < 4194304; i += stride) {
        float4 v = ((const float4*)x)[i];
        *(f16x4*)(xb + (size_t)i * 4) = f16x4{ (f16)v.x, (f16)v.y, (f16)v.z, (f16)v.w };
    }
    for (int i = tid; i < 196608; i += stride) {
        float4 v = ((const float4*)wqkv)[i];
        *(f16x4*)(wqb + (size_t)i * 4) = f16x4{ (f16)v.x, (f16)v.y, (f16)v.z, (f16)v.w };
    }
    for (int i = tid; i < 65536; i += stride) {
        float4 v = ((const float4*)wout)[i];
        *(f16x4*)(wob + (size_t)i * 4) = f16x4{ (f16)v.x, (f16)v.y, (f16)v.z, (f16)v.w };
    }
}

#define W0  asm volatile("s_waitcnt vmcnt(0)" ::: "memory")
#define BAR __builtin_amdgcn_s_barrier()

// ============ ENGINE A2: g15 = merged QKV (g10 structure, runtime qk) =========
// 128x128 tile, BK=64, 4 waves, dbuf 64KB LDS, 2 blocks/CU (r6-verified core).
// Blocks 0..2047: Q/K n-tiles (normal mfma, permuted A rows) -> [bh][c][lh].
// Blocks 2048..3071: V n-tiles (swapped mfma) -> [bh][lh][d].
// Single dispatch: V blocks backfill CUs during the QK tail.

#define A_STAGE(NB) do {                                                        \
    gload16(Ab + kb + sE,          &ldsA[NB][( 0 + wid*8)*64]);                 \
    gload16(Ab + kb + sO + 32768,  &ldsA[NB][(32 + wid*8)*64]);                 \
    gload16(Ab + kb + sE + 65536,  &ldsA[NB][(64 + wid*8)*64]);                 \
    gload16(Ab + kb + sO + 98304,  &ldsA[NB][(96 + wid*8)*64]);                 \
    gload16(Bb + kb + sE,          &ldsB[NB][( 0 + wid*8)*64]);                 \
    gload16(Bb + kb + sO + 32768,  &ldsB[NB][(32 + wid*8)*64]);                 \
    gload16(Bb + kb + sE + 65536,  &ldsB[NB][(64 + wid*8)*64]);                 \
    gload16(Bb + kb + sO + 98304,  &ldsB[NB][(96 + wid*8)*64]);                 \
    kb += 128;                                                                  \
} while (0)

#define A_RD(SET, BUF) do {                                                     \
    _Pragma("unroll") for (int mi = 0; mi < 4; ++mi)                            \
    _Pragma("unroll") for (int kk = 0; kk < 2; ++kk)                            \
        aF##SET[mi][kk] = *(const f16x8*)(&ldsA[BUF][0] + aoff[mi][kk]);        \
    _Pragma("unroll") for (int ni = 0; ni < 4; ++ni)                            \
    _Pragma("unroll") for (int kk = 0; kk < 2; ++kk)                            \
        bF##SET[ni][kk] = *(const f16x8*)(&ldsB[BUF][0] + boff[ni][kk]);        \
} while (0)

#define A_MM(SET, KK, ML, MH_) do {                                             \
    __builtin_amdgcn_s_setprio(1);                                              \
    if (qk) {                                                                   \
        _Pragma("unroll") for (int mi = ML; mi < MH_; ++mi)                     \
        _Pragma("unroll") for (int ni = 0; ni < 4; ++ni)                        \
            acc[mi][ni] = __builtin_amdgcn_mfma_f32_16x16x32_f16(               \
                aF##SET[mi][KK], bF##SET[ni][KK], acc[mi][ni], 0, 0, 0);        \
    } else {                                                                    \
        _Pragma("unroll") for (int mi = ML; mi < MH_; ++mi)                     \
        _Pragma("unroll") for (int ni = 0; ni < 4; ++ni)                        \
            acc[mi][ni] = __builtin_amdgcn_mfma_f32_16x16x32_f16(               \
                bF##SET[ni][KK], aF##SET[mi][KK], acc[mi][ni], 0, 0, 0);        \
    }                                                                           \
    __builtin_amdgcn_s_setprio(0);                                              \
} while (0)

#define A_MM3(SET)   do { A_MM(SET, 0, 0, 2); A_MM(SET, 0, 2, 4); A_MM(SET, 1, 0, 2); } while (0)
#define A_MMLAST(SET) A_MM(SET, 1, 2, 4)

#define A_TILE(CUR, NXT, NB, STG, FINAL) do {                                   \
    if (STG) A_STAGE(NB);                                                       \
    A_MM3(CUR);                                                                 \
    if (!FINAL) { W0; BAR; A_RD(NXT, NB); }                                     \
    A_MMLAST(CUR);                                                              \
} while (0)

__global__ __launch_bounds__(256, 2) void g15_k(const f16* __restrict__ A0,
                                                const f16* __restrict__ B0,
                                                f16* __restrict__ Qd,
                                                f16* __restrict__ Kd,
                                                f16* __restrict__ Vd) {
    __shared__ f16 ldsA[2][8192];
    __shared__ f16 ldsB[2][8192];

    const int tid = threadIdx.x;
    const int lane = tid & 63;
    const int wid = tid >> 6;
    const int wr = wid >> 1;
    const int wc = wid & 1;

    const int bid = blockIdx.x;
    const bool qk = bid < 2048;
    int tm, tn;
    if (qk) {
        int swz = (bid & 7) * 256 + (bid >> 3);       // 2048 QK blocks
        tm = (swz >> 3) * 128; tn = (swz & 7) * 128;
    } else {
        int b2 = bid - 2048;
        int swz = (b2 & 7) * 128 + (b2 >> 3);         // 1024 V blocks
        tm = (swz >> 2) * 128; tn = (swz & 3) * 128 + 1024;
    }

    const char* Ab = (const char*)(A0 + (size_t)tm * 512);
    const char* Bb = (const char*)(B0 + (size_t)tn * 512);

    const int u = tid >> 3;
    const int colE = ((tid & 7) ^ ((u & 7) ^ (u >> 3))) * 16;
    const int sE = u * 1024 + colE;
    const int sO = sE ^ 64;
    int kb = 0;

    int aoff[4][2], boff[4][2];
#pragma unroll
    for (int mi = 0; mi < 4; ++mi) {
        int r = qk ? ((lane & 15) * 8 + wr * 4 + mi)
                   : (wr * 64 + mi * 16 + (lane & 15));
#pragma unroll
        for (int kk = 0; kk < 2; ++kk) {
            int c8 = (lane >> 4) + kk * 4;
            aoff[mi][kk] = r * 64 + (c8 ^ ((r & 7) ^ ((r >> 3) & 7))) * 8;
        }
    }
#pragma unroll
    for (int ni = 0; ni < 4; ++ni) {
        int r = wc * 64 + ni * 16 + (lane & 15);
#pragma unroll
        for (int kk = 0; kk < 2; ++kk) {
            int c8 = (lane >> 4) + kk * 4;
            boff[ni][kk] = r * 64 + (c8 ^ ((r & 7) ^ ((r >> 3) & 7))) * 8;
        }
    }

    f32x4 acc[4][4] = {};
    f16x8 aF0[4][2], bF0[4][2], aF1[4][2], bF1[4][2];

    A_STAGE(0);
    W0; BAR;
    A_RD(0, 0);

#pragma unroll 1
    for (int i = 0; i < 3; ++i) {
        A_TILE(0, 1, 1, true, false);
        A_TILE(1, 0, 0, true, false);
    }
    A_TILE(0, 1, 1, true, false);   // t6
    A_TILE(1, 1, 1, false, true);   // t7

    if (qk) {
        const int b = tm >> 12;
        const int lt = (tm & 4095) >> 3;
        f16* dst = (tn < 512) ? Qd : Kd;
        const int cb = (tn & 511) + wc * 64;
        const int lh0 = lt + (lane >> 4) * 4;
#pragma unroll
        for (int mi = 0; mi < 4; ++mi) {
            int h = wr * 4 + mi;
#pragma unroll
            for (int ni = 0; ni < 4; ++ni) {
                int c = cb + ni * 16 + (lane & 15);
                *(f16x4*)(dst + ((size_t)((b * 8 + h) * 512 + c)) * 512 + lh0) =
                    cvt4(acc[mi][ni]);
            }
        }
    } else {                       // V, swapped
        f16* dst = Vd;
#pragma unroll
        for (int mi = 0; mi < 4; ++mi) {
            int t = tm + wr * 64 + mi * 16 + (lane & 15);
            int b = t >> 12, l = t & 4095;
            int h = l & 7, lh = l >> 3;
#pragma unroll
            for (int ni = 0; ni < 4; ++ni) {
                int d0 = (tn - 1024) + wc * 64 + ni * 16 + (lane >> 4) * 4;
                *(f16x4*)(dst + ((size_t)((b * 8 + h) * 512 + lh)) * 512 + d0) =
                    cvt4(acc[mi][ni]);
            }
        }
    }
}

// ================== ENGINE S: fused S-GEMM + softmax (r12 verbatim) ===========
#define S_STAGE(B) do {                                                         \
    gload16(Qt + kb + soff,           &ldsQ[B][(  0 + wid*8)*64]);              \
    gload16(Qt + kb + soff + 65536,   &ldsQ[B][( 64 + wid*8)*64]);              \
    gload16(Kt + kb + soff,           &ldsK[B][(  0 + wid*8)*64]);              \
    gload16(Kt + kb + soff + 65536,   &ldsK[B][( 64 + wid*8)*64]);              \
    gload16(Kt + kb + soff + 131072,  &ldsK[B][(128 + wid*8)*64]);              \
    gload16(Kt + kb + soff + 196608,  &ldsK[B][(192 + wid*8)*64]);              \
    gload16(Kt + kb + soff + 262144,  &ldsK[B][(256 + wid*8)*64]);              \
    gload16(Kt + kb + soff + 327680,  &ldsK[B][(320 + wid*8)*64]);              \
    gload16(Kt + kb + soff + 393216,  &ldsK[B][(384 + wid*8)*64]);              \
    gload16(Kt + kb + soff + 458752,  &ldsK[B][(448 + wid*8)*64]);              \
    kb += 128;                                                                  \
} while (0)

#define S_RD(KK, B) do {                                                        \
    _Pragma("unroll") for (int ni = 0; ni < 4; ++ni)                            \
        bF[ni] = *(const f16x8*)(&ldsK[B][0] + boff[ni][KK]);                   \
    _Pragma("unroll") for (int mi = 0; mi < 8; ++mi)                            \
        aF[mi] = *(const f16x8*)(&ldsQ[B][0] + aoff[mi][KK]);                   \
} while (0)

#define S_MM do {                                                               \
    __builtin_amdgcn_s_setprio(1);                                              \
    _Pragma("unroll") for (int mi = 0; mi < 8; ++mi)                            \
    _Pragma("unroll") for (int ni = 0; ni < 4; ++ni)                            \
        acc[mi][ni] = __builtin_amdgcn_mfma_f32_16x16x32_f16(                   \
            aF[mi], bF[ni], acc[mi][ni], 0, 0, 0);                              \
    __builtin_amdgcn_s_setprio(0);                                              \
} while (0)

__global__ __launch_bounds__(512) void sfm_k(const f16* __restrict__ Qb,
                                             const f16* __restrict__ Kb,
                                             f16* __restrict__ Pb) {
    __shared__ f16 ldsQ[2][8192];     // 32 KB
    __shared__ f16 ldsK[2][32768];    // 128 KB

    const int tid = threadIdx.x;
    const int lane = tid & 63;
    const int wid = tid >> 6;
    const int g = lane >> 4;
    const int li = lane & 15;

    const int bid = blockIdx.x;
    const int swz = (bid & 7) * 32 + (bid >> 3);
    const int bh = swz >> 2, ct = swz & 3;

    const char* Qt = (const char*)(Qb + (size_t)bh * 262144 + (size_t)ct * 128 * 512);
    const char* Kt = (const char*)(Kb + (size_t)bh * 262144);

    const int soff = (tid >> 3) * 1024 +
                     ((((lane & 7) ^ (lane >> 3) ^ wid) & 7) * 16);
    int kb = 0;

    int aoff[8][2], boff[4][2];
#pragma unroll
    for (int mi = 0; mi < 8; ++mi) {
        int r = mi * 16 + li;
        int s3 = (r & 7) ^ ((r >> 3) & 7);
#pragma unroll
        for (int kk = 0; kk < 2; ++kk)
            aoff[mi][kk] = r * 64 + (((g + kk * 4) ^ s3)) * 8;
    }
#pragma unroll
    for (int ni = 0; ni < 4; ++ni) {
        int r = wid * 64 + ni * 16 + li;
        int s3 = (r & 7) ^ ((r >> 3) & 7);
#pragma unroll
        for (int kk = 0; kk < 2; ++kk)
            boff[ni][kk] = r * 64 + (((g + kk * 4) ^ s3)) * 8;
    }

    f32x4 acc[8][4] = {};
    f16x8 aF[8], bF[4];

    S_STAGE(0);
#pragma unroll 1
    for (int t = 0; t < 8; ++t) {
        const int cb = t & 1;
        if (t < 7) {
            S_STAGE(cb ^ 1);
            asm volatile("s_waitcnt vmcnt(10)" ::: "memory");
        } else {
            W0;
        }
        BAR;
        S_RD(0, cb);
        S_MM;
        S_RD(1, cb);
        S_MM;
        BAR;
    }

    float* red  = (float*)&ldsQ[0][0];
    float* redg = (float*)&ldsK[0][0];

#pragma unroll
    for (int mi = 0; mi < 8; ++mi)
#pragma unroll
        for (int ni = 0; ni < 4; ++ni) acc[mi][ni] *= 0.125f;

#pragma unroll
    for (int mi = 0; mi < 8; ++mi)
#pragma unroll
        for (int j = 0; j < 4; ++j) {
            float v = fmaxf(fmaxf(acc[mi][0][j], acc[mi][1][j]),
                            fmaxf(acc[mi][2][j], acc[mi][3][j]));
#pragma unroll
            for (int off = 1; off < 16; off <<= 1) v = fmaxf(v, __shfl_xor(v, off, 64));
            if (li == 0) red[wid * 128 + mi * 16 + g * 4 + j] = v;
        }
    BAR;
    if (tid < 128) {
        float m = red[tid];
#pragma unroll
        for (int w = 1; w < 8; ++w) m = fmaxf(m, red[w * 128 + tid]);
        redg[tid] = m;
    }
    BAR;

#pragma unroll
    for (int mi = 0; mi < 8; ++mi)
#pragma unroll
        for (int j = 0; j < 4; ++j) {
            float mg = redg[mi * 16 + g * 4 + j];
            float s = 0.f;
#pragma unroll
            for (int ni = 0; ni < 4; ++ni) {
                float e = __expf(acc[mi][ni][j] - mg);
                acc[mi][ni][j] = e;
                s += e;
            }
#pragma unroll
            for (int off = 1; off < 16; off <<= 1) s += __shfl_xor(s, off, 64);
            if (li == 0) red[wid * 128 + mi * 16 + g * 4 + j] = s;
        }
    BAR;
    if (tid < 128) {
        float s = red[tid];
#pragma unroll
        for (int w = 1; w < 8; ++w) s += red[w * 128 + tid];
        redg[tid] = 1.0f / s;
    }
    BAR;

    f16* Pt = Pb + (size_t)bh * 262144;
#pragma unroll
    for (int mi = 0; mi < 8; ++mi)
#pragma unroll
        for (int j = 0; j < 4; ++j) {
            int row = mi * 16 + g * 4 + j;
            float is = redg[row];
            size_t base = (size_t)(ct * 128 + row) * 512 + wid * 64 + li;
#pragma unroll
            for (int ni = 0; ni < 4; ++ni)
                Pt[base + ni * 16] = (f16)(acc[mi][ni][j] * is);
        }
}

// ======================= ENGINE B: g12 (r12 verbatim) =========================
#define B_STAGE(NB) do {                                                        \
    gload16(At + soff,          &ldsA2[NB][(  0 + wid*8)*64]);                  \
    gload16(At + soff + 65536,  &ldsA2[NB][( 64 + wid*8)*64]);                  \
    gload16(At + soff + 131072, &ldsA2[NB][(128 + wid*8)*64]);                  \
    gload16(At + soff + 196608, &ldsA2[NB][(192 + wid*8)*64]);                  \
    gload16(Bt + soff,          &ldsB2[NB][(  0 + wid*8)*64]);                  \
    gload16(Bt + soff + 65536,  &ldsB2[NB][( 64 + wid*8)*64]);                  \
    gload16(Bt + soff + 131072, &ldsB2[NB][(128 + wid*8)*64]);                  \
    gload16(Bt + soff + 196608, &ldsB2[NB][(192 + wid*8)*64]);                  \
    At += 128; Bt += 128;                                                       \
} while (0)

#define B_RD12(KK, BUF) do {                                                    \
    _Pragma("unroll") for (int ni = 0; ni < 4; ++ni)                            \
        bF[ni] = *(const f16x8*)(&ldsB2[BUF][0] + boff[ni][KK]);                \
    _Pragma("unroll") for (int mi = 0; mi < 8; ++mi)                            \
        aF[mi] = *(const f16x8*)(&ldsA2[BUF][0] + aoff[mi][KK]);                \
} while (0)

#define B_MM32 do {                                                             \
    __builtin_amdgcn_s_setprio(1);                                              \
    _Pragma("unroll") for (int mi = 0; mi < 8; ++mi)                            \
    _Pragma("unroll") for (int ni = 0; ni < 4; ++ni) {                          \
        if constexpr (SWP)                                                      \
            acc[mi][ni] = __builtin_amdgcn_mfma_f32_16x16x32_f16(               \
                bF[ni], aF[mi], acc[mi][ni], 0, 0, 0);                          \
        else                                                                    \
            acc[mi][ni] = __builtin_amdgcn_mfma_f32_16x16x32_f16(               \
                aF[mi], bF[ni], acc[mi][ni], 0, 0, 0);                          \
    }                                                                           \
    __builtin_amdgcn_s_setprio(0);                                              \
} while (0)

#define B_TILE(CB, NB, STG, FINAL) do {                                         \
    B_RD12(0, CB);                                                              \
    if (STG) B_STAGE(NB);                                                       \
    B_MM32;                                                                     \
    B_RD12(1, CB);                                                              \
    B_MM32;                                                                     \
    if (!FINAL) { W0; BAR; }                                                    \
} while (0)

// MODE 2: Y = P V per bh (normal, f16 out to y[token][c])
// MODE 3: out = y w_out^T + b_out (swapped, f32 out)
template <int MODE, bool SWP>
__global__ __launch_bounds__(512) void g12_k(const f16* __restrict__ A0,
                                             const f16* __restrict__ B0,
                                             void* __restrict__ C0,
                                             const float* __restrict__ bias) {
    __shared__ f16 ldsA2[2][16384];
    __shared__ f16 ldsB2[2][16384];

    const int tid = threadIdx.x;
    const int lane = tid & 63;
    const int wid = tid >> 6;
    const int wr = wid >> 2;
    const int wc = wid & 3;

    const int bid = blockIdx.x;
    int tm, tn, bh = 0;
    if constexpr (MODE == 2) {
        int swz = (bid & 7) * 32 + (bid >> 3);        // 256 blocks
        bh = swz >> 2; tm = ((swz >> 1) & 1) * 256; tn = (swz & 1) * 256;
    } else {
        int swz = (bid & 7) * 32 + (bid >> 3);        // 256 blocks
        tm = (swz >> 1) * 256; tn = (swz & 1) * 256;
    }

    const size_t bhoff = (MODE == 2) ? (size_t)bh * 262144 : 0;
    const char* At = (const char*)(A0 + bhoff + (size_t)tm * 512);
    const char* Bt = (const char*)(B0 + bhoff + (size_t)tn * 512);

    const int soff = wid * 8192 + (lane >> 3) * 1024 +
                     ((((lane & 7) ^ (lane >> 3) ^ wid) & 7) * 16);

    int aoff[8][2], boff[4][2];
#pragma unroll
    for (int mi = 0; mi < 8; ++mi) {
        int r = wr * 128 + mi * 16 + (lane & 15);
        int s3 = (r & 7) ^ ((r >> 3) & 7);
#pragma unroll
        for (int kk = 0; kk < 2; ++kk)
            aoff[mi][kk] = r * 64 + ((((lane >> 4) + kk * 4) ^ s3)) * 8;
    }
#pragma unroll
    for (int ni = 0; ni < 4; ++ni) {
        int r = wc * 64 + ni * 16 + (lane & 15);
        int s3 = (r & 7) ^ ((r >> 3) & 7);
#pragma unroll
        for (int kk = 0; kk < 2; ++kk)
            boff[ni][kk] = r * 64 + ((((lane >> 4) + kk * 4) ^ s3)) * 8;
    }

    f32x4 acc[8][4] = {};
    f16x8 aF[8], bF[4];

    B_STAGE(0);
    W0; BAR;

#pragma unroll 1
    for (int i = 0; i < 3; ++i) {
        B_TILE(0, 1, true, false);
        B_TILE(1, 0, true, false);
    }
    B_TILE(0, 1, true, false);    // t6
    B_TILE(1, 1, false, true);    // t7

    if constexpr (MODE == 2) {
        f16* yb = (f16*)C0;
        const int b = bh >> 3, h = bh & 7;
#pragma unroll
        for (int mi = 0; mi < 8; ++mi) {
            int c0 = tm + wr * 128 + mi * 16 + (lane >> 4) * 4;
#pragma unroll
            for (int ni = 0; ni < 4; ++ni) {
                int l = tn + wc * 64 + ni * 16 + (lane & 15);
                size_t tok = (size_t)b * 4096 + (size_t)l * 8 + h;
                *(f16x4*)(yb + tok * 512 + c0) = cvt4(acc[mi][ni]);
            }
        }
    } else {
        float* O = (float*)C0;
#pragma unroll
        for (int mi = 0; mi < 8; ++mi) {
            int m = tm + wr * 128 + mi * 16 + (lane & 15);
#pragma unroll
            for (int ni = 0; ni < 4; ++ni) {
                int n0 = tn + wc * 64 + ni * 16 + (lane >> 4) * 4;
                float4 bv = *(const float4*)(bias + n0);
                f32x4 v = acc[mi][ni];
                v[0] += bv.x; v[1] += bv.y; v[2] += bv.z; v[3] += bv.w;
                *(f32x4*)(O + (size_t)m * 512 + n0) = v;
            }
        }
    }
}

// ---------------- launch ------------------------------------------------------
extern "C" void kernel_launch(void* const* d_in, const int* in_sizes, int n_in,
                              void* d_out, int out_size, void* d_ws, size_t ws_size,
                              hipStream_t stream) {
    const float* x = (const float*)d_in[0];
    const float* wqkv = (const float*)d_in[1];
    const float* wout = (const float*)d_in[2];
    const float* bout = (const float*)d_in[3];
    float* out = (float*)d_out;
    char* ws = (char*)d_ws;
    const size_t MBs = 1u << 20;

    f16* xb  = (f16*)(ws + 0);            // 32MB
    f16* wqb = (f16*)(ws + 32 * MBs);     // 1.5MB
    f16* wob = (f16*)(ws + 34 * MBs);     // 0.5MB
    f16* Qb  = (f16*)(ws + 35 * MBs);     // 32MB
    f16* Kb  = (f16*)(ws + 67 * MBs);     // 32MB
    f16* Vb  = (f16*)(ws + 99 * MBs);     // 32MB
    f16* Pb  = xb;                        // alias: xb dead after QKV GEMM
    f16* yb  = Qb;                        // alias: Q dead after sfm

    prep_k<<<1024, 256, 0, stream>>>(x, wqkv, wout, xb, wqb, wob);
    g15_k<<<3072, 256, 0, stream>>>(xb, wqb, Qb, Kb, Vb);
    sfm_k<<<256, 512, 0, stream>>>(Qb, Kb, Pb);
    g12_k<2, false><<<256, 512, 0, stream>>>(Pb, Vb, yb, nullptr);
    g12_k<3, true><<<256, 512, 0, stream>>>(yb, wob, out, bout);
}